// Round 3
// baseline (199.013 us; speedup 1.0000x reference)
//
#include <hip/hip_runtime.h>
#include <stdint.h>

// Cost volume: out[b,k,h,w] = (1/81) * sum_c x1[b,c,h,w] * x2[b,c,h-i,w-j]
// k = (9i+j) mod 81, i,j in [-4,4], zero-padded x2. B=4 C=128 H=128 W=256 fp32.
//
// R8 = R7 resubmit (R7 bench died in the broker, not in the kernel; source
// re-audited: LDS bounds, staging decode, swizzle bijectivity all OK).
//
// R7: targeted conflict + locality fixes (R5/R6 showed structure-invariant
// ~87us with everything idle; 8.6M LDS conflict cycles ~16% of CU time).
//  - Epilogue scratch TRANSPOSED to [hl][m 16][kk 81]: m-stride 82 floats
//    (82*4 = 328 = 8 mod 32 -> quad offsets 0/8/16/24), hl-stride 1313 (odd).
//    Scatter banks = 8*quad + ja -> <=2-way (was ~4.5-way: old layout had
//    every contribution = 0 mod 4 except reg -> 8-bank residue collapse).
//    Readback: 4 scalar ds_reads, banks hlx + 8*m4 + kk -> 2 lanes/bank.
//  - x2 staging decode reordered (f4 slowest, cp fastest): per-wave f4 is
//    uniform, rows span 4 -> write banks 4*dr+cp <=4-way (was 6-way from
//    row r / r+8 collision at word-stride 4 mod 32).
//  - XCD-aware tile swizzle: ltile = (local%8)*32 + local/8 -> each XCD owns
//    2 contiguous h-rows x all w; x2 halo (h +-4 / w +-4 overlap) becomes
//    same-XCD L2 hits instead of HBM re-fetch.
//  - Keeps R6 double-buffered pipeline, cvt_pk, setprio.
//
// Toeplitz window: D[m][n] = sum_c x1[c, w0+m] * x2[c, h-i, w0-4+n]
//   -> out(w0+m, j) = D[m][m+4-j], window 24 cols = 2x mfma_f32_16x16x32_bf16.
// Block: 1024 thr = 16 waves = (hl 0..7) x (igrp 0..1); tile 8h x 16w.

#define HH 128
#define WW 256
#define HW 32768
#define DD 81
#define NT 1024

typedef __attribute__((ext_vector_type(8))) short short8;
typedef __attribute__((ext_vector_type(4))) float float4v;

// staging geometry (ushorts)
#define A_ROW 648   // 16 m * 40 + 8 pad
#define B_ROW 1288  // 32 wcol * 40 + 8 pad
#define KSTR 40     // 32 bf16 + 8 pad
#define B_BASE 5184 // A region = 8 * 648
#define PER_BUF 25792  // ushorts per buffer (51584 B)
// epilogue scratch: [8 hl][16 m][81 kk], m-stride 82, hl-stride 1313 floats
#define EP_M 82
#define EP_H 1313   // 16*82 + 1 (odd -> readback hlx spreads banks)

__device__ __forceinline__ uint32_t cvt_pk_bf16(float lo, float hi) {
  uint32_t r;
  asm("v_cvt_pk_bf16_f32 %0, %1, %2" : "=v"(r) : "v"(lo), "v"(hi));
  return r;
}

template <int NI, int I0>
__device__ __forceinline__ void compute_chunk(const unsigned short* buf, int hl,
                                              int n16, int quad, float4v* acc0,
                                              float4v* acc1) {
  const short8 a = *(const short8*)(buf + hl * A_ROW + n16 * KSTR + quad * 8);
  __builtin_amdgcn_s_setprio(1);
#pragma unroll
  for (int ii = 0; ii < NI; ++ii) {
    const int row = hl - (I0 + ii) + 4;  // 0..15
    const unsigned short* bp = buf + B_BASE + row * B_ROW + n16 * KSTR + quad * 8;
    const short8 b0 = *(const short8*)(bp);
    const short8 b1 = *(const short8*)(bp + 16 * KSTR);
    acc0[ii] = __builtin_amdgcn_mfma_f32_16x16x32_bf16(a, b0, acc0[ii], 0, 0, 0);
    acc1[ii] = __builtin_amdgcn_mfma_f32_16x16x32_bf16(a, b1, acc1[ii], 0, 0, 0);
  }
  __builtin_amdgcn_s_setprio(0);
}

__global__ __launch_bounds__(NT, 4) void cost_volume_kernel(
    const float* __restrict__ x1, const float* __restrict__ x2,
    float* __restrict__ out, const float* __restrict__ zws) {
  __shared__ unsigned short smem[2 * PER_BUF];  // 103168 B, 1 block/CU

  const int b = blockIdx.z;
  // XCD-aware swizzle: hw assigns XCD = dispatch_id % 8; remap so each XCD
  // owns a contiguous 2-h-row x 16-w-tile region (halo stays in XCD L2).
  const int local = blockIdx.y * 16 + blockIdx.x;        // 0..255
  const int lt = (local & 7) * 32 + (local >> 3);        // bijective remap
  const int h0 = (lt >> 4) * 8;
  const int w0 = (lt & 15) * 16;
  const int t = threadIdx.x;
  const int wid = t >> 6;
  const int hl = wid & 7;
  const int igrp = wid >> 3;
  const int lane = t & 63;
  const int n16 = lane & 15;
  const int quad = lane >> 4;

  const float* x1b = x1 + (size_t)b * 128 * HW;
  const float* x2b = x2 + (size_t)b * 128 * HW;

  // ---- decode this thread's two staging tasks (chunk-invariant parts) ----
  const float* tbase[2];
  int tgoff[2], tlds[2], tcp[2];
  bool tok[2];
#pragma unroll
  for (int s = 0; s < 2; ++s) {
    const int tau = t + s * NT;
    if (tau < 512) {
      const int cp = tau >> 5, rem = tau & 31, row = rem >> 2, f4 = rem & 3;
      tbase[s] = x1b;
      tgoff[s] = (h0 + row) * WW + w0 + f4 * 4;
      tlds[s] = row * A_ROW + f4 * 160 + 2 * cp;
      tcp[s] = cp;
      tok[s] = true;
    } else {
      const int tp = tau - 512;  // 0..1535
      // f4 slowest / cp fastest: per-wave f4 uniform, rows span 4
      // -> staging-write banks 4*dr + cp (<=4-way, was 6-way)
      const int f4 = tp >> 8;          // 0..5
      const int row = (tp >> 4) & 15;  // 0..15
      const int cp = tp & 15;          // 0..15
      const int h2 = h0 - 4 + row;
      const int wg = w0 - 4 + f4 * 4;
      tbase[s] = x2b;
      tgoff[s] = h2 * WW + wg;
      tlds[s] = B_BASE + row * B_ROW + f4 * 160 + 2 * cp;
      tcp[s] = cp;
      tok[s] = ((unsigned)h2 < (unsigned)HH) && ((unsigned)wg <= (unsigned)(WW - 4));
    }
  }

  float4v acc0[5], acc1[5];
#pragma unroll
  for (int ii = 0; ii < 5; ++ii) {
    acc0[ii] = (float4v){0.f, 0.f, 0.f, 0.f};
    acc1[ii] = (float4v){0.f, 0.f, 0.f, 0.f};
  }

  float4 va0[2], vb0[2], va1[2], vb1[2];

#define LOADSET(VA, VB, C0)                                                    \
  {                                                                            \
    _Pragma("unroll") for (int s = 0; s < 2; ++s) {                            \
      const float* p =                                                         \
          tok[s] ? tbase[s] + (size_t)((C0) + 2 * tcp[s]) * HW + tgoff[s]      \
                 : zws;                                                        \
      const float* q = tok[s] ? p + HW : zws;                                  \
      VA[s] = *(const float4*)p;                                               \
      VB[s] = *(const float4*)q;                                               \
    }                                                                          \
  }

#define CONVSET(VA, VB, BUFSEL)                                                \
  {                                                                            \
    _Pragma("unroll") for (int s = 0; s < 2; ++s) {                            \
      unsigned short* dst = smem + (BUFSEL) * PER_BUF + tlds[s];               \
      const float4 fa = VA[s];                                                 \
      const float4 fb = VB[s];                                                 \
      *(uint32_t*)(dst + 0 * KSTR) = cvt_pk_bf16(fa.x, fb.x);                  \
      *(uint32_t*)(dst + 1 * KSTR) = cvt_pk_bf16(fa.y, fb.y);                  \
      *(uint32_t*)(dst + 2 * KSTR) = cvt_pk_bf16(fa.z, fb.z);                  \
      *(uint32_t*)(dst + 3 * KSTR) = cvt_pk_bf16(fa.w, fb.w);                  \
    }                                                                          \
  }

#define COMPUTE(BUFSEL)                                                        \
  {                                                                            \
    const unsigned short* cbuf = smem + (BUFSEL) * PER_BUF;                    \
    if (igrp == 0)                                                             \
      compute_chunk<5, -4>(cbuf, hl, n16, quad, acc0, acc1);                   \
    else                                                                       \
      compute_chunk<4, 1>(cbuf, hl, n16, quad, acc0, acc1);                    \
  }

  // ---- software-pipelined main loop: 4 chunks of 32 channels ----
  LOADSET(va0, vb0, 0);
  LOADSET(va1, vb1, 32);
  CONVSET(va0, vb0, 0);
  __syncthreads();  // buf0 visible

  LOADSET(va0, vb0, 64);
  COMPUTE(0);
  CONVSET(va1, vb1, 1);
  __syncthreads();

  LOADSET(va1, vb1, 96);
  COMPUTE(1);
  CONVSET(va0, vb0, 0);
  __syncthreads();

  COMPUTE(0);
  CONVSET(va1, vb1, 1);
  __syncthreads();

  COMPUTE(1);
  __syncthreads();  // all compute reads done; reuse smem as fp32 scratch

  // ---- epilogue: scatter D-fragments to LDS scratch, read back coalesced ---
  // scratch layout [hl][m][kk]: scatter banks = 8*quad + ja (<=2-way)
  float* scratch = (float*)smem;  // 8*1313 = 10504 floats = 42016 B
  const float sc = 1.0f / 81.0f;
  const int ni = igrp ? 4 : 5;
  const int i0 = igrp ? 1 : -4;
#pragma unroll 5
  for (int ii = 0; ii < 5; ++ii) {
    if (ii >= ni) break;
    const int iabs = (i0 + ii) + 4;
    const float av0[4] = {acc0[ii].x, acc0[ii].y, acc0[ii].z, acc0[ii].w};
    const float av1[4] = {acc1[ii].x, acc1[ii].y, acc1[ii].z, acc1[ii].w};
#pragma unroll
    for (int reg = 0; reg < 4; ++reg) {
      const int m = quad * 4 + reg;
      // tile0: window col n16 -> j = m + 4 - n16
      {
        const unsigned ja = (unsigned)(m + 4 - n16 + 4);
        if (ja < 9u)
          scratch[hl * EP_H + m * EP_M + iabs * 9 + (int)ja] = av0[reg] * sc;
      }
      // tile1: window col 16+n16 -> j = m - 12 - n16
      {
        const unsigned ja = (unsigned)(m - 12 - n16 + 4);
        if (ja < 9u)
          scratch[hl * EP_H + m * EP_M + iabs * 9 + (int)ja] = av1[reg] * sc;
      }
    }
  }
  __syncthreads();

  // coalesced write-out: f -> (kk81, hlx, m4); 4 scalar LDS reads per float4
  // (banks hlx + 8*m4 + kk: 2 lanes/bank, conflict-free)
  for (int f = t; f < 2592; f += NT) {
    const int m4 = f & 3;
    const int hlx = (f >> 2) & 7;
    const int kk81 = f >> 5;  // iabs*9 + jabs
    float4 v;
    v.x = scratch[hlx * EP_H + (m4 * 4 + 0) * EP_M + kk81];
    v.y = scratch[hlx * EP_H + (m4 * 4 + 1) * EP_M + kk81];
    v.z = scratch[hlx * EP_H + (m4 * 4 + 2) * EP_M + kk81];
    v.w = scratch[hlx * EP_H + (m4 * 4 + 3) * EP_M + kk81];
    const int kk = (kk81 + 41) % 81;
    *(float4*)(out + (((size_t)b * DD + kk) * HH + (h0 + hlx)) * WW + w0 +
               m4 * 4) = v;
  }
}

extern "C" void kernel_launch(void* const* d_in, const int* in_sizes, int n_in,
                              void* d_out, int out_size, void* d_ws,
                              size_t ws_size, hipStream_t stream) {
  const float* x1 = (const float*)d_in[0];
  const float* x2 = (const float*)d_in[1];
  float* out = (float*)d_out;

  // zero 256 B of workspace: OOB staging lanes read zeros from here
  hipMemsetAsync(d_ws, 0, 256, stream);

  dim3 grid(WW / 16, HH / 8, 4);  // 16 x 16 x 4 = 1024 blocks
  dim3 block(NT);
  hipLaunchKernelGGL(cost_volume_kernel, grid, block, 0, stream, x1, x2, out,
                     (const float*)d_ws);
}

// Round 4
// 194.975 us; speedup vs baseline: 1.0207x; 1.0207x over previous
//
#include <hip/hip_runtime.h>
#include <stdint.h>

// Cost volume: out[b,k,h,w] = (1/81) * sum_c x1[b,c,h,w] * x2[b,c,h-i,w-j]
// k = (9i+j) mod 81, i,j in [-4,4], zero-padded x2. B=4 C=128 H=128 W=256 fp32.
//
// R9: counted-barrier pipeline (T4). Root cause of the structure-invariant
// ~87-93us across R5/R6/R8: __syncthreads() emits s_waitcnt vmcnt(0) before
// s_barrier, DRAINING the prefetch loads at every chunk boundary -> the R6
// "pipeline" never existed; every chunk paid a full loaded-chip HBM round
// trip with nothing to cover it (1 block/CU).
//  - All barriers -> {s_waitcnt lgkmcnt(0); s_barrier} (LDS visibility only).
//    Global prefetch loads stay in flight across barriers; compiler inserts
//    exact vmcnt(4) at the va/vb register uses (4 newer loads outstanding).
//  - Single 51.5 KB LDS buffer -> 2 blocks/CU (32-wave cap) for cross-block
//    latency hiding; prefetch is register-carried (2 load-sets), so LDS
//    double-buffering is unnecessary. Per-chunk: [CONVSET; prefetch-issue;
//    bar] [COMPUTE; bar(WAR)].
//  - Reverted R8 regressions: XCD swizzle (L3-fit case: FETCH halved but
//    time +7%) and x2 decode reorder (scattered each staging load across 16
//    channel-pairs, 256KB apart -> per-instruction global scatter).
//  - Kept: cvt_pk_bf16, setprio around MFMA, transposed epilogue scratch
//    [hl][m][kk] (conflicts 8.6M -> 4.5M, real).
//
// Toeplitz window: D[m][n] = sum_c x1[c, w0+m] * x2[c, h-i, w0-4+n]
//   -> out(w0+m, j) = D[m][m+4-j], window 24 cols = 2x mfma_f32_16x16x32_bf16.
// Block: 1024 thr = 16 waves = (hl 0..7) x (igrp 0..1); tile 8h x 16w.

#define HH 128
#define WW 256
#define HW 32768
#define DD 81
#define NT 1024

typedef __attribute__((ext_vector_type(8))) short short8;
typedef __attribute__((ext_vector_type(4))) float float4v;

// staging geometry (ushorts)
#define A_ROW 648   // 16 m * 40 + 8 pad
#define B_ROW 1288  // 32 wcol * 40 + 8 pad
#define KSTR 40     // 32 bf16 + 8 pad
#define B_BASE 5184 // A region = 8 * 648
#define PER_BUF 25792  // ushorts (51584 B) -> 3 LDS-wise, 2 by 32-wave cap
// epilogue scratch: [8 hl][16 m][81 kk], m-stride 82, hl-stride 1313 floats
#define EP_M 82
#define EP_H 1313   // 16*82 + 1

// LDS-only barrier: does NOT drain vmcnt (the whole point).
#define BAR()                                                \
  {                                                          \
    asm volatile("s_waitcnt lgkmcnt(0)" ::: "memory");       \
    __builtin_amdgcn_s_barrier();                            \
    asm volatile("" ::: "memory");                           \
  }

__device__ __forceinline__ uint32_t cvt_pk_bf16(float lo, float hi) {
  uint32_t r;
  asm("v_cvt_pk_bf16_f32 %0, %1, %2" : "=v"(r) : "v"(lo), "v"(hi));
  return r;
}

template <int NI, int I0>
__device__ __forceinline__ void compute_chunk(const unsigned short* buf, int hl,
                                              int n16, int quad, float4v* acc0,
                                              float4v* acc1) {
  const short8 a = *(const short8*)(buf + hl * A_ROW + n16 * KSTR + quad * 8);
  __builtin_amdgcn_s_setprio(1);
#pragma unroll
  for (int ii = 0; ii < NI; ++ii) {
    const int row = hl - (I0 + ii) + 4;  // 0..15
    const unsigned short* bp = buf + B_BASE + row * B_ROW + n16 * KSTR + quad * 8;
    const short8 b0 = *(const short8*)(bp);
    const short8 b1 = *(const short8*)(bp + 16 * KSTR);
    acc0[ii] = __builtin_amdgcn_mfma_f32_16x16x32_bf16(a, b0, acc0[ii], 0, 0, 0);
    acc1[ii] = __builtin_amdgcn_mfma_f32_16x16x32_bf16(a, b1, acc1[ii], 0, 0, 0);
  }
  __builtin_amdgcn_s_setprio(0);
}

__global__ __launch_bounds__(NT, 4) void cost_volume_kernel(
    const float* __restrict__ x1, const float* __restrict__ x2,
    float* __restrict__ out, const float* __restrict__ zws) {
  __shared__ unsigned short smem[PER_BUF];  // 51584 B -> 2 blocks/CU

  const int b = blockIdx.z;
  const int h0 = blockIdx.y * 8;
  const int w0 = blockIdx.x * 16;
  const int t = threadIdx.x;
  const int wid = t >> 6;
  const int hl = wid & 7;
  const int igrp = wid >> 3;
  const int lane = t & 63;
  const int n16 = lane & 15;
  const int quad = lane >> 4;

  const float* x1b = x1 + (size_t)b * 128 * HW;
  const float* x2b = x2 + (size_t)b * 128 * HW;

  // ---- decode this thread's two staging tasks (chunk-invariant parts) ----
  const float* tbase[2];
  int tgoff[2], tlds[2], tcp[2];
  bool tok[2];
#pragma unroll
  for (int s = 0; s < 2; ++s) {
    const int tau = t + s * NT;
    if (tau < 512) {
      const int cp = tau >> 5, rem = tau & 31, row = rem >> 2, f4 = rem & 3;
      tbase[s] = x1b;
      tgoff[s] = (h0 + row) * WW + w0 + f4 * 4;
      tlds[s] = row * A_ROW + f4 * 160 + 2 * cp;
      tcp[s] = cp;
      tok[s] = true;
    } else {
      const int tp = tau - 512;  // 0..1535  (cp slowest: wave-contiguous loads)
      const int cp = tp / 96, rem = tp - cp * 96, row = rem / 6,
                f4 = rem - row * 6;
      const int h2 = h0 - 4 + row;
      const int wg = w0 - 4 + f4 * 4;
      tbase[s] = x2b;
      tgoff[s] = h2 * WW + wg;
      tlds[s] = B_BASE + row * B_ROW + f4 * 160 + 2 * cp;
      tcp[s] = cp;
      tok[s] = ((unsigned)h2 < (unsigned)HH) && ((unsigned)wg <= (unsigned)(WW - 4));
    }
  }

  float4v acc0[5], acc1[5];
#pragma unroll
  for (int ii = 0; ii < 5; ++ii) {
    acc0[ii] = (float4v){0.f, 0.f, 0.f, 0.f};
    acc1[ii] = (float4v){0.f, 0.f, 0.f, 0.f};
  }

  float4 va0[2], vb0[2], va1[2], vb1[2];

#define LOADSET(VA, VB, C0)                                                    \
  {                                                                            \
    _Pragma("unroll") for (int s = 0; s < 2; ++s) {                            \
      const float* p =                                                         \
          tok[s] ? tbase[s] + (size_t)((C0) + 2 * tcp[s]) * HW + tgoff[s]      \
                 : zws;                                                        \
      const float* q = tok[s] ? p + HW : zws;                                  \
      VA[s] = *(const float4*)p;                                               \
      VB[s] = *(const float4*)q;                                               \
    }                                                                          \
  }

#define CONVSET(VA, VB)                                                        \
  {                                                                            \
    _Pragma("unroll") for (int s = 0; s < 2; ++s) {                            \
      unsigned short* dst = smem + tlds[s];                                    \
      const float4 fa = VA[s];                                                 \
      const float4 fb = VB[s];                                                 \
      *(uint32_t*)(dst + 0 * KSTR) = cvt_pk_bf16(fa.x, fb.x);                  \
      *(uint32_t*)(dst + 1 * KSTR) = cvt_pk_bf16(fa.y, fb.y);                  \
      *(uint32_t*)(dst + 2 * KSTR) = cvt_pk_bf16(fa.z, fb.z);                  \
      *(uint32_t*)(dst + 3 * KSTR) = cvt_pk_bf16(fa.w, fb.w);                  \
    }                                                                          \
  }

#define COMPUTE()                                                              \
  {                                                                            \
    if (igrp == 0)                                                             \
      compute_chunk<5, -4>(smem, hl, n16, quad, acc0, acc1);                   \
    else                                                                       \
      compute_chunk<4, 1>(smem, hl, n16, quad, acc0, acc1);                    \
  }

  // ---- counted-barrier pipeline: 4 chunks of 32 channels, 1 LDS buffer ----
  // Loads for chunks k+1, k+2 always in flight; barriers never drain vmcnt.
  LOADSET(va0, vb0, 0);
  LOADSET(va1, vb1, 32);

  // k=0
  CONVSET(va0, vb0);        // waits vmcnt(4) for c0 loads only
  LOADSET(va0, vb0, 64);    // c2 in flight
  BAR();                    // staged c0 visible
  COMPUTE();
  BAR();                    // WAR: all frag reads done before restage
  // k=1
  CONVSET(va1, vb1);
  LOADSET(va1, vb1, 96);    // c3 in flight
  BAR();
  COMPUTE();
  BAR();
  // k=2
  CONVSET(va0, vb0);
  BAR();
  COMPUTE();
  BAR();
  // k=3
  CONVSET(va1, vb1);
  BAR();
  COMPUTE();
  BAR();  // WAR: frag reads done before scratch overwrite

  // ---- epilogue: scatter D-fragments to LDS scratch, read back coalesced ---
  // scratch layout [hl][m][kk]: scatter banks = 8*quad + ja (<=2-way)
  float* scratch = (float*)smem;  // 10504 floats = 42016 B < 51584 B
  const float sc = 1.0f / 81.0f;
  const int ni = igrp ? 4 : 5;
  const int i0 = igrp ? 1 : -4;
#pragma unroll 5
  for (int ii = 0; ii < 5; ++ii) {
    if (ii >= ni) break;
    const int iabs = (i0 + ii) + 4;
    const float av0[4] = {acc0[ii].x, acc0[ii].y, acc0[ii].z, acc0[ii].w};
    const float av1[4] = {acc1[ii].x, acc1[ii].y, acc1[ii].z, acc1[ii].w};
#pragma unroll
    for (int reg = 0; reg < 4; ++reg) {
      const int m = quad * 4 + reg;
      // tile0: window col n16 -> j = m + 4 - n16
      {
        const unsigned ja = (unsigned)(m + 4 - n16 + 4);
        if (ja < 9u)
          scratch[hl * EP_H + m * EP_M + iabs * 9 + (int)ja] = av0[reg] * sc;
      }
      // tile1: window col 16+n16 -> j = m - 12 - n16
      {
        const unsigned ja = (unsigned)(m - 12 - n16 + 4);
        if (ja < 9u)
          scratch[hl * EP_H + m * EP_M + iabs * 9 + (int)ja] = av1[reg] * sc;
      }
    }
  }
  BAR();  // scatter visible

  // coalesced write-out: f -> (kk81, hlx, m4); 4 scalar LDS reads per float4
  for (int f = t; f < 2592; f += NT) {
    const int m4 = f & 3;
    const int hlx = (f >> 2) & 7;
    const int kk81 = f >> 5;  // iabs*9 + jabs
    float4 v;
    v.x = scratch[hlx * EP_H + (m4 * 4 + 0) * EP_M + kk81];
    v.y = scratch[hlx * EP_H + (m4 * 4 + 1) * EP_M + kk81];
    v.z = scratch[hlx * EP_H + (m4 * 4 + 2) * EP_M + kk81];
    v.w = scratch[hlx * EP_H + (m4 * 4 + 3) * EP_M + kk81];
    const int kk = (kk81 + 41) % 81;
    *(float4*)(out + (((size_t)b * DD + kk) * HH + (h0 + hlx)) * WW + w0 +
               m4 * 4) = v;
  }
}

extern "C" void kernel_launch(void* const* d_in, const int* in_sizes, int n_in,
                              void* d_out, int out_size, void* d_ws,
                              size_t ws_size, hipStream_t stream) {
  const float* x1 = (const float*)d_in[0];
  const float* x2 = (const float*)d_in[1];
  float* out = (float*)d_out;

  // zero 256 B of workspace: OOB staging lanes read zeros from here
  hipMemsetAsync(d_ws, 0, 256, stream);

  dim3 grid(WW / 16, HH / 8, 4);  // 16 x 16 x 4 = 1024 blocks
  dim3 block(NT);
  hipLaunchKernelGGL(cost_volume_kernel, grid, block, 0, stream, x1, x2, out,
                     (const float*)d_ws);
}